// Round 4
// baseline (91.813 us; speedup 1.0000x reference)
//
#include <hip/hip_runtime.h>

// GaussianImage Cholesky render — per-wave tile rasterizer.
// N=20000 gaussians, 256x256x3 image, CHW float32 out.
// Each 64-lane wave owns one (16x16-px tile, gaussian-slice) task:
// no __syncthreads, no LDS, no atomics. Survivors found by __ballot,
// params broadcast from the finder lane via v_readlane (scalar regs).

#define N_G   20000
#define IMG_H 256
#define IMG_W 256
#define TILE  16
#define NTILES 256          // 16x16 tiles
#define MAX_SLICES 16
#define CUT_T 18.0f         // exp(-18)=1.5e-8; worst-case culled sum 3e-4 << 2e-2
#define LOG2E 1.4426950408889634f

__device__ __forceinline__ float rl(float v, int j) {
    return __int_as_float(__builtin_amdgcn_readlane(__float_as_int(v), j));
}

// ---------------- preprocess ----------------
__global__ __launch_bounds__(256) void gs_preprocess(
    const float* __restrict__ xyz,   // (N,2)
    const float* __restrict__ chol,  // (N,3)
    const float* __restrict__ fdc,   // (N,3)
    const float* __restrict__ rgbw,  // (N,1)
    float4* __restrict__ a0,         // bbox (x0,x1,y0,y1)
    float4* __restrict__ a1,         // (cx, cy, 0.5*ca*log2e, cb*log2e)
    float4* __restrict__ a2)         // (0.5*cc*log2e, fr, fg, fb)
{
    int gi = blockIdx.x * 256 + threadIdx.x;
    if (gi >= N_G) return;
    float l1 = chol[3 * gi + 0] + 0.5f;
    float l2 = chol[3 * gi + 1];
    float l3 = chol[3 * gi + 2] + 0.5f;
    float s11 = l1 * l1;
    float s12 = l1 * l2;
    float s22 = l2 * l2 + l3 * l3;
    float det = s11 * s22 - s12 * s12;     // = l1^2 l3^2 > 0 (PD)
    float inv = 1.0f / det;
    float ca = s22 * inv;
    float cb = -s12 * inv;
    float cc = s11 * inv;
    float cx = 0.5f * (float)IMG_W * (tanhf(xyz[2 * gi + 0]) + 1.0f) - 0.5f;
    float cy = 0.5f * (float)IMG_H * (tanhf(xyz[2 * gi + 1]) + 1.0f) - 0.5f;
    float rx = sqrtf(2.0f * CUT_T * s11);  // max |dx| on sigma<=T ellipse
    float ry = sqrtf(2.0f * CUT_T * s22);
    float wgt = rgbw[gi];
    a0[gi] = make_float4(cx - rx, cx + rx, cy - ry, cy + ry);
    a1[gi] = make_float4(cx, cy, 0.5f * ca * LOG2E, cb * LOG2E);
    a2[gi] = make_float4(0.5f * cc * LOG2E, fdc[3 * gi + 0] * wgt,
                         fdc[3 * gi + 1] * wgt, fdc[3 * gi + 2] * wgt);
}

// ---------------- per-wave tile rasterizer ----------------
// task = blockIdx.x*4 + waveid; tile = task & 255, slice = task >> 8.
// Lane l covers 4 pixels: x = tx0 + (l&15), y = ty0 + (l>>4)*4 + k, k=0..3.
__global__ __launch_bounds__(256) void gs_tiles(
    const float4* __restrict__ a0,
    const float4* __restrict__ a1,
    const float4* __restrict__ a2,
    float* __restrict__ partial,   // [slice][3][H][W]
    int g_per_slice)
{
    const int tid  = threadIdx.x;
    const int lane = tid & 63;
    const int task = blockIdx.x * 4 + (tid >> 6);
    const int tile = task & (NTILES - 1);
    const int slice = task >> 8;
    const int tx0 = (tile & 15) * TILE;
    const int ty0 = (tile >> 4) * TILE;
    const float pxf = (float)(tx0 + (lane & 15));
    const float py0 = (float)(ty0 + ((lane >> 4) << 2));
    const float txmin = (float)tx0, txmax = (float)(tx0 + TILE - 1);
    const float tymin = (float)ty0, tymax = (float)(ty0 + TILE - 1);

    const int g0 = slice * g_per_slice;
    const int g1 = min(N_G, g0 + g_per_slice);

    float acc[12];
    #pragma unroll
    for (int i = 0; i < 12; ++i) acc[i] = 0.0f;

    // pipelined first load
    int gi = g0 + lane;
    float4 bb = make_float4(1.e30f, -1.e30f, 1.e30f, -1.e30f);
    float4 v1 = make_float4(0, 0, 0, 0), v2 = make_float4(0, 0, 0, 0);
    if (gi < g1) { bb = a0[gi]; v1 = a1[gi]; v2 = a2[gi]; }

    for (int base = g0; base < g1; base += 64) {
        bool ok = (base + lane < g1) &&
                  bb.x <= txmax && bb.y >= txmin && bb.z <= tymax && bb.w >= tymin;
        unsigned long long mask = __ballot(ok);

        // prefetch next round while we process survivors
        float4 nbb = bb, nv1 = v1, nv2 = v2;
        int ngi = base + 64 + lane;
        if (base + 64 < g1) {
            if (ngi < g1) { nbb = a0[ngi]; nv1 = a1[ngi]; nv2 = a2[ngi]; }
            else nbb = make_float4(1.e30f, -1.e30f, 1.e30f, -1.e30f);
        }

        while (mask) {
            int j = __ffsll((unsigned long long)mask) - 1;
            mask &= mask - 1;
            float cx  = rl(v1.x, j), cy  = rl(v1.y, j);
            float cah = rl(v1.z, j), cbs = rl(v1.w, j);
            float cch = rl(v2.x, j);
            float fr  = rl(v2.y, j), fg = rl(v2.z, j), fb = rl(v2.w, j);
            float dx  = pxf - cx;
            float t0  = cah * dx * dx;
            float bdx = cbs * dx;
            #pragma unroll
            for (int k = 0; k < 4; ++k) {
                float dy = (py0 + (float)k) - cy;
                float s  = fmaf(cch * dy, dy, fmaf(bdx, dy, t0));
                float w  = exp2f(-fmaxf(s, 0.0f));
                acc[3 * k + 0] = fmaf(w, fr, acc[3 * k + 0]);
                acc[3 * k + 1] = fmaf(w, fg, acc[3 * k + 1]);
                acc[3 * k + 2] = fmaf(w, fb, acc[3 * k + 2]);
            }
        }
        bb = nbb; v1 = nv1; v2 = nv2;
    }

    const int plane = IMG_H * IMG_W;
    float* dst = partial + (size_t)slice * 3 * plane;
    const int x = tx0 + (lane & 15);
    const int y0i = ty0 + ((lane >> 4) << 2);
    #pragma unroll
    for (int k = 0; k < 4; ++k) {
        int pix = (y0i + k) * IMG_W + x;
        dst[pix] = acc[3 * k + 0];
        dst[plane + pix] = acc[3 * k + 1];
        dst[2 * plane + pix] = acc[3 * k + 2];
    }
}

// ---------------- reduce slices + clip, CHW output ----------------
__global__ __launch_bounds__(256) void gs_reduce(
    const float4* __restrict__ partial, float4* __restrict__ out, int slices)
{
    const int total4 = 3 * IMG_H * IMG_W / 4;   // 49152 float4
    int i = blockIdx.x * 256 + threadIdx.x;
    if (i >= total4) return;
    float4 s = make_float4(0, 0, 0, 0);
    for (int sl = 0; sl < slices; ++sl) {
        float4 p = partial[(size_t)sl * total4 + i];
        s.x += p.x; s.y += p.y; s.z += p.z; s.w += p.w;
    }
    s.x = fminf(fmaxf(s.x, 0.0f), 1.0f);
    s.y = fminf(fmaxf(s.y, 0.0f), 1.0f);
    s.z = fminf(fmaxf(s.z, 0.0f), 1.0f);
    s.w = fminf(fmaxf(s.w, 0.0f), 1.0f);
    out[i] = s;
}

extern "C" void kernel_launch(void* const* d_in, const int* in_sizes, int n_in,
                              void* d_out, int out_size, void* d_ws, size_t ws_size,
                              hipStream_t stream) {
    const float* xyz  = (const float*)d_in[0];
    const float* chol = (const float*)d_in[1];
    const float* fdc  = (const float*)d_in[2];
    const float* rgbw = (const float*)d_in[3];

    char* ws = (char*)d_ws;
    float4* a0 = (float4*)(ws);
    float4* a1 = (float4*)(ws + (size_t)N_G * 16);
    float4* a2 = (float4*)(ws + (size_t)N_G * 32);
    float*  partial = (float*)(ws + (size_t)N_G * 48);

    const size_t gbytes = (size_t)N_G * 48;
    const size_t per_slice = (size_t)3 * IMG_H * IMG_W * sizeof(float);
    int slices = MAX_SLICES;
    while (slices > 1 && gbytes + (size_t)slices * per_slice > ws_size)
        slices >>= 1;
    int gps = (N_G + slices - 1) / slices;

    gs_preprocess<<<(N_G + 255) / 256, 256, 0, stream>>>(
        xyz, chol, fdc, rgbw, a0, a1, a2);
    // NTILES*slices wave-tasks, 4 waves (256 threads) per block
    gs_tiles<<<(NTILES * slices) / 4, 256, 0, stream>>>(
        a0, a1, a2, partial, gps);
    gs_reduce<<<(3 * IMG_H * IMG_W / 4 + 255) / 256, 256, 0, stream>>>(
        (const float4*)partial, (float4*)d_out, slices);
}